// Round 4
// baseline (244.640 us; speedup 1.0000x reference)
//
#include <hip/hip_runtime.h>
#include <hip/hip_fp16.h>
#include <stdint.h>
#include <math.h>

#define T_STEPS 4096
#define BATCH   256
#define NB_BLK  256      // 16-step spike blocks (scan2/3 bitmap granularity)
#define NSEG    1024     // 4-step cert segments per batch
#define EPITCH  1025     // [c][seg] pitch in float2 units (bank spread)

// LIF step, threshold=1:  v'=alpha*v+xs; s=max(floor(v'),0); v=v'-s
// Identity: v_new = min(v', fract(v')); s = v' - v_new (exact fp32).
__device__ __forceinline__ float lif_step(float& v, float xs, float alpha) {
    float vp = fmaf(alpha, v, xs);
    float fr = vp - floorf(vp);
    float vn = fminf(vp, fr);
    float s  = vp - vn;
    v = vn;
    return s;
}

__device__ __forceinline__ float ubf(uint32_t w, int k) {
    return (float)((w >> (k * 8)) & 0xffu);
}

__device__ __forceinline__ float dot16(const float wr[16],
    float4 c0, float4 c1, float4 c2, float4 c3)
{
    float p0 = fmaf(wr[1], c0.y, wr[0] * c0.x);
    p0 = fmaf(wr[2], c0.z, p0);  p0 = fmaf(wr[3], c0.w, p0);
    float p1 = fmaf(wr[5], c1.y, wr[4] * c1.x);
    p1 = fmaf(wr[6], c1.z, p1);  p1 = fmaf(wr[7], c1.w, p1);
    float p2 = fmaf(wr[9], c2.y, wr[8] * c2.x);
    p2 = fmaf(wr[10], c2.z, p2); p2 = fmaf(wr[11], c2.w, p2);
    float p3 = fmaf(wr[13], c3.y, wr[12] * c3.x);
    p3 = fmaf(wr[14], c3.z, p3); p3 = fmaf(wr[15], c3.w, p3);
    return (p0 + p1) + (p2 + p3);
}

// R17: NO x-LDS, NO chunk loop.  Evidence: R14/R15/R16 all paid ~17-20us per
// 64KB chunk regardless of staging mechanism (DMA vs reg) and chunk size ->
// the chunked LDS round-trip structure (16x-broadcast ds_read river + chunk
// synchronization) is the cost, not any one staging path.  New decomposition:
// thread tid owns 4 consecutive steps (= 1 cert segment) and computes ALL 16
// channels itself: 256B of x -> 16 dwordx4 into registers (L1 absorbs the 4x
// line split: p>0 quads hit the lines p=0 fetched), weights are wave-uniform
// -> scalar loads.  LDS holds ONLY cert summaries: float2 {end fp32,
// (m1h<<16|m0h) f16} at [c][seg] pitch 1025 (131KB).  f16 m0/m1 biased +1e-3
// before RNE convert -> always >= true value (sound; decoded bound can only
// over-flag).  Composition: 16ch x 8 eighths (128 lanes), 40-seg warm-up
// (alpha4^40 = 3.4e-4 < the 1e-3 guard band).  Repair: per-wave channel,
// 4-step exact segs from global x, jump via cert .x elsewhere.  Tails
// (scan2/scan3) kept fused and LDS-flag gated (never run on this data:
// layer-1 membrane sigma~0.16 vs threshold 1 => P(spike)~1e-10).
__global__ __launch_bounds__(1024, 4) void fused(
    const float* __restrict__ x, const float* __restrict__ w1,
    const float* __restrict__ w2, const float* __restrict__ w3,
    float* __restrict__ out, uint8_t* __restrict__ s1t,
    uint8_t* __restrict__ s2t,
    float alpha, float one_m, float alpha4)
{
    const int tid = threadIdx.x;
    const int b   = blockIdx.x;
    const int wv  = tid >> 6;
    const int ln  = tid & 63;

    __shared__ float2   sh_cert[16][EPITCH];   // 131.2 KiB: {end, m01(f16x2)}
    __shared__ uint32_t sh_badseg[16][NSEG / 32];   // 2 KiB
    __shared__ uint8_t  sh_bm1[NB_BLK];             // 256 B
    __shared__ uint8_t  sh_bm2[NB_BLK];             // 256 B
    __shared__ int      sh_badch, sh_spike, sh_flag2;

    const float* xb = x + (size_t)b * T_STEPS * 16;      // 65536 floats
    const float4* xq4 = (const float4*)xb;               // 16384 float4

    // ---- my 4 rows (= segment tid) straight into registers ----------------
    float4 xr[16];
#pragma unroll
    for (int q = 0; q < 16; ++q) xr[q] = xq4[tid * 16 + q];

    // ---- LDS flag/bitmap init ---------------------------------------------
    if (tid < 64)        ((uint32_t*)sh_bm1)[tid] = 0u;
    else if (tid < 128)  ((uint32_t*)sh_bm2)[tid - 64] = 0u;
    else if (tid == 128) { sh_badch = 0; sh_spike = 0; sh_flag2 = 0; }

    // ---- zero out[b] (overlaps x-load latency) ----------------------------
    float4* o4 = (float4*)(out + (size_t)b * T_STEPS * 10);   // 10240 float4
    float4 z4 = make_float4(0.f, 0.f, 0.f, 0.f);
#pragma unroll
    for (int i = 0; i < 10; ++i) o4[i * 1024 + tid] = z4;

    // ---- all 16 channels for my 4 steps; write cert summaries -------------
#pragma unroll 2
    for (int c = 0; c < 16; ++c) {
        float wc[16];
#pragma unroll
        for (int i = 0; i < 16; ++i) wc[i] = w1[c * 16 + i];   // uniform->SGPR
        float acc = 0.0f, m0 = -1e30f, m1 = -1e30f, pw = alpha;
#pragma unroll
        for (int j = 0; j < 4; ++j) {
            float y = dot16(wc, xr[j*4+0], xr[j*4+1], xr[j*4+2], xr[j*4+3]);
            acc = fmaf(alpha, acc, one_m * y);
            m0  = fmaxf(m0, acc);
            m1  = fmaxf(m1, acc + pw);
            pw *= alpha;
        }
        // f16 round-up encode: +1e-3 bias > half-ulp for |m|<=2; larger m
        // always decodes >= ~2 and flags bad anyway -> sound.
        unsigned short h0 = __half_as_ushort(__float2half(m0 + 1e-3f));
        unsigned short h1 = __half_as_ushort(__float2half(m1 + 1e-3f));
        uint32_t enc = ((uint32_t)h1 << 16) | (uint32_t)h0;
        sh_cert[c][tid] = make_float2(acc, __uint_as_float(enc));
    }
    __syncthreads();   // all cert entries visible

    // ---- composition + certification: 16 ch x 8 eighths (128 lanes) -------
    if (tid < 128) {
        const int c  = tid & 15;
        const int e8 = tid >> 4;
        const int s0 = e8 * 128;
        float vs = 0.0f;
        if (e8 > 0) {   // 40-seg warm-up: alpha4^40 = e^-8 = 3.4e-4 carry err
#pragma unroll 8
            for (int s = s0 - 40; s < s0; ++s)
                vs = fmaf(alpha4, vs, sh_cert[c][s].x);
        }
        uint32_t bw = 0;
        int bad = 0;
#pragma unroll 8
        for (int s = s0; s < s0 + 128; ++s) {
            float2 ct = sh_cert[c][s];
            uint32_t enc = __float_as_uint(ct.y);
            float m0v = __half2float(__ushort_as_half((unsigned short)(enc & 0xffffu)));
            float m1v = __half2float(__ushort_as_half((unsigned short)(enc >> 16)));
            float vsu = fminf(fmaxf(vs + 1e-3f, 0.0f), 1.0f);
            float bound = fmaf(1.0f - vsu, m0v, vsu * m1v);
            if (!(bound < 0.999f)) { bw |= 1u << (s & 31); bad = 1; }  // NaN->bad
            if ((s & 31) == 31) { sh_badseg[c][s >> 5] = bw; bw = 0; }
            vs = fmaf(alpha4, vs, ct.x);
        }
        if (bad) atomicOr(&sh_badch, 1 << c);
    }
    __syncthreads();

    // ---- parallel exact repair for cert-bad channels (rare) ---------------
    const int badmask = sh_badch;
    if (badmask) {
        // dense-zero s1t[b] so the scan2 phase never reads unwritten bytes
        uint4* sz = (uint4*)(s1t + (size_t)b * 16 * T_STEPS);
#pragma unroll
        for (int i = 0; i < 4; ++i) sz[i * 1024 + tid] = make_uint4(0u,0u,0u,0u);
        __syncthreads();   // zeroing ordered before repair spike writes

        int m = badmask;
        for (int i = 0; i < wv; ++i) m &= m - 1;
        if (ln == 0 && m) {
            const int c = __ffs(m) - 1;
            float wc[16];
#pragma unroll
            for (int i = 0; i < 16; ++i) wc[i] = w1[c * 16 + i];
            uint8_t* op = s1t + ((size_t)b * 16 + c) * T_STEPS;
            float v = 0.0f;
            int any = 0;
            for (int w32 = 0; w32 < 32; ++w32) {
                uint32_t bwv = sh_badseg[c][w32];
                const int sb = w32 * 32;
                if (bwv == 0u) {
#pragma unroll 8
                    for (int q = 0; q < 32; ++q)
                        v = fmaf(alpha4, v, sh_cert[c][sb + q].x);
                } else {
                    for (int q = 0; q < 32; ++q) {
                        const int s = sb + q;
                        if (!((bwv >> q) & 1u)) {
                            v = fmaf(alpha4, v, sh_cert[c][s].x);
                            continue;
                        }
                        const float4* xr2 = xq4 + (size_t)s * 16;
                        uint32_t sw = 0u;
#pragma unroll
                        for (int j = 0; j < 4; ++j) {
                            float y = dot16(wc, xr2[j*4+0], xr2[j*4+1],
                                                 xr2[j*4+2], xr2[j*4+3]);
                            float sp = lif_step(v, one_m * y, alpha);
                            sw |= ((uint32_t)(int)sp) << (j * 8);
                        }
                        if (sw) {
                            *(uint32_t*)(op + s * 4) = sw;
                            sh_bm1[s >> 2] = 1;
                            any = 1;
                        }
                    }
                }
            }
            if (any) sh_spike = 1;
        }
    }
    __syncthreads();   // orders repair writes + sh_spike/sh_bm1 for readers

    // ---- fused layer-2: sparse scan s1t -> s2t (+ sh_bm2) -----------------
    if (sh_spike) {
        if (tid < 32) {
            const int c2 = tid;
            float wr2[16];
#pragma unroll
            for (int i = 0; i < 16; ++i) wr2[i] = one_m * w2[c2 * 16 + i];
            const uint8_t* sb1 = s1t + (size_t)b * 16 * T_STEPS;
            uint4* op2 = (uint4*)(s2t + ((size_t)b * 32 + c2) * T_STEPS);
            const uint4* bmv = (const uint4*)sh_bm1;
            float v = 0.0f;
            for (int sb = 0; sb < 16; ++sb) {
                uint4 bm = bmv[sb];
                if ((bm.x | bm.y | bm.z | bm.w) == 0u) {
                    if (v != 0.0f) {
                        for (int blk = 0; blk < 16 && v != 0.0f; ++blk) {
#pragma unroll
                            for (int j = 0; j < 16; ++j) v *= alpha;
                        }
                    }
                    continue;
                }
                for (int blk = 0; blk < 16; ++blk) {
                    uint32_t d = (blk < 4) ? bm.x : (blk < 8) ? bm.y
                               : (blk < 12) ? bm.z : bm.w;
                    uint32_t byte = (d >> ((blk & 3) * 8)) & 0xffu;
                    if (byte == 0u) {
                        if (v != 0.0f) {
#pragma unroll
                            for (int j = 0; j < 16; ++j) v *= alpha;
                        }
                        continue;
                    }
                    const int tb = sb * 16 + blk;
                    const int t0 = tb * 16;
                    uint4 S[16];
#pragma unroll
                    for (int c = 0; c < 16; ++c)
                        S[c] = *(const uint4*)(sb1 + (size_t)c * T_STEPS + t0);
                    uint32_t w[4] = {0u, 0u, 0u, 0u};
#pragma unroll
                    for (int j = 0; j < 16; ++j) {
                        float xv[16];
#pragma unroll
                        for (int c = 0; c < 16; ++c) {
                            uint32_t dd = (j < 4) ? S[c].x : (j < 8) ? S[c].y
                                        : (j < 12) ? S[c].z : S[c].w;
                            xv[c] = ubf(dd, j & 3);
                        }
                        float p0 = fmaf(wr2[1], xv[1], wr2[0] * xv[0]);
                        p0 = fmaf(wr2[2], xv[2], p0);   p0 = fmaf(wr2[3], xv[3], p0);
                        float p1 = fmaf(wr2[5], xv[5], wr2[4] * xv[4]);
                        p1 = fmaf(wr2[6], xv[6], p1);   p1 = fmaf(wr2[7], xv[7], p1);
                        float p2 = fmaf(wr2[9], xv[9], wr2[8] * xv[8]);
                        p2 = fmaf(wr2[10], xv[10], p2); p2 = fmaf(wr2[11], xv[11], p2);
                        float p3 = fmaf(wr2[13], xv[13], wr2[12] * xv[12]);
                        p3 = fmaf(wr2[14], xv[14], p3); p3 = fmaf(wr2[15], xv[15], p3);
                        float xs = (p0 + p1) + (p2 + p3);
                        float s = lif_step(v, xs, alpha);
                        w[j >> 2] |= ((uint32_t)(int)s) << ((j & 3) * 8);
                    }
                    op2[tb] = make_uint4(w[0], w[1], w[2], w[3]);
                    if (w[0] | w[1] | w[2] | w[3]) { sh_bm2[tb] = 1; sh_flag2 = 1; }
                }
            }
        }
        __syncthreads();   // s2t/sh_bm2/sh_flag2 visible

        // ---- fused layer-3: sparse scan s2t -> out (pre-zeroed) -----------
        if (sh_flag2 && tid < 16) {
            const int c3 = tid;
            const bool active = (c3 < 10);
            float wr3[32];
#pragma unroll
            for (int i = 0; i < 32; ++i)
                wr3[i] = active ? (one_m * w3[c3 * 32 + i]) : 0.0f;
            const uint8_t* sb2 = s2t + (size_t)b * 32 * T_STEPS;
            const uint4* bmv2 = (const uint4*)sh_bm2;
            float* ob = out + (size_t)b * T_STEPS * 10 + c3;
            float v = 0.0f;
            for (int sb = 0; sb < 16; ++sb) {
                uint4 bm = bmv2[sb];
                if ((bm.x | bm.y | bm.z | bm.w) == 0u) {
                    if (v != 0.0f) {
                        for (int blk = 0; blk < 16 && v != 0.0f; ++blk) {
#pragma unroll
                            for (int j = 0; j < 16; ++j) v *= alpha;
                        }
                    }
                    continue;
                }
                for (int blk = 0; blk < 16; ++blk) {
                    uint32_t d = (blk < 4) ? bm.x : (blk < 8) ? bm.y
                               : (blk < 12) ? bm.z : bm.w;
                    uint32_t byte = (d >> ((blk & 3) * 8)) & 0xffu;
                    if (byte == 0u) {
                        if (v != 0.0f) {
#pragma unroll
                            for (int j = 0; j < 16; ++j) v *= alpha;
                        }
                        continue;
                    }
                    const int t0 = (sb * 16 + blk) * 16;
                    uint4 S[32];
#pragma unroll
                    for (int c = 0; c < 32; ++c)
                        S[c] = *(const uint4*)(sb2 + (size_t)c * T_STEPS + t0);
#pragma unroll
                    for (int j = 0; j < 16; ++j) {
                        float xv[32];
#pragma unroll
                        for (int c = 0; c < 32; ++c) {
                            uint32_t dd = (j < 4) ? S[c].x : (j < 8) ? S[c].y
                                        : (j < 12) ? S[c].z : S[c].w;
                            xv[c] = ubf(dd, j & 3);
                        }
                        float p0 = fmaf(wr3[1], xv[1], wr3[0] * xv[0]);
                        p0 = fmaf(wr3[2],  xv[2],  p0); p0 = fmaf(wr3[3],  xv[3],  p0);
                        p0 = fmaf(wr3[4],  xv[4],  p0); p0 = fmaf(wr3[5],  xv[5],  p0);
                        p0 = fmaf(wr3[6],  xv[6],  p0); p0 = fmaf(wr3[7],  xv[7],  p0);
                        float p1 = fmaf(wr3[9], xv[9], wr3[8] * xv[8]);
                        p1 = fmaf(wr3[10], xv[10], p1); p1 = fmaf(wr3[11], xv[11], p1);
                        p1 = fmaf(wr3[12], xv[12], p1); p1 = fmaf(wr3[13], xv[13], p1);
                        p1 = fmaf(wr3[14], xv[14], p1); p1 = fmaf(wr3[15], xv[15], p1);
                        float p2 = fmaf(wr3[17], xv[17], wr3[16] * xv[16]);
                        p2 = fmaf(wr3[18], xv[18], p2); p2 = fmaf(wr3[19], xv[19], p2);
                        p2 = fmaf(wr3[20], xv[20], p2); p2 = fmaf(wr3[21], xv[21], p2);
                        p2 = fmaf(wr3[22], xv[22], p2); p2 = fmaf(wr3[23], xv[23], p2);
                        float p3 = fmaf(wr3[25], xv[25], wr3[24] * xv[24]);
                        p3 = fmaf(wr3[26], xv[26], p3); p3 = fmaf(wr3[27], xv[27], p3);
                        p3 = fmaf(wr3[28], xv[28], p3); p3 = fmaf(wr3[29], xv[29], p3);
                        p3 = fmaf(wr3[30], xv[30], p3); p3 = fmaf(wr3[31], xv[31], p3);
                        float xs = (p0 + p1) + (p2 + p3);
                        float s = lif_step(v, xs, alpha);
                        if (active && s != 0.0f) ob[(size_t)(t0 + j) * 10] = s;
                    }
                }
            }
        }
    }
}

extern "C" void kernel_launch(void* const* d_in, const int* in_sizes, int n_in,
                              void* d_out, int out_size, void* d_ws, size_t ws_size,
                              hipStream_t stream)
{
    const float* data = (const float*)d_in[0];
    const float* w1   = (const float*)d_in[1];
    const float* w2   = (const float*)d_in[2];
    const float* w3   = (const float*)d_in[3];
    float* out = (float*)d_out;

    // ws layout (48 MiB):
    //   [0, 16M)    s1t  u8 [256][16][4096]  (dense-zeroed only for bad b)
    //   [16M, 48M)  s2t  u8 [256][32][4096]  (sparse: only bm2-set blocks valid)
    uint8_t* ws  = (uint8_t*)d_ws;
    uint8_t* s1t = ws;
    uint8_t* s2t = ws + (16u << 20);

    const float alpha  = expf(-1.0f / 20.0f);
    const float one_m  = 1.0f - alpha;
    const float alpha4 = expf(-4.0f / 20.0f);

    fused<<<BATCH, 1024, 0, stream>>>(data, w1, w2, w3, out, s1t, s2t,
                                      alpha, one_m, alpha4);
}

// Round 5
// 228.293 us; speedup vs baseline: 1.0716x; 1.0716x over previous
//
#include <hip/hip_runtime.h>
#include <stdint.h>
#include <math.h>

#define T_STEPS 4096
#define BATCH   256
#define NB_BLK  256      // 16-step spike blocks (scan2/3 bitmap granularity)
#define NSEG    1024     // 4-step cert segments per batch
#define EPITCH  1025     // [c][seg] pitch in float2 units (bank spread)

// LIF step, threshold=1:  v'=alpha*v+xs; s=max(floor(v'),0); v=v'-s
// Identity: v_new = min(v', fract(v')); s = v' - v_new (exact fp32).
__device__ __forceinline__ float lif_step(float& v, float xs, float alpha) {
    float vp = fmaf(alpha, v, xs);
    float fr = vp - floorf(vp);
    float vn = fminf(vp, fr);
    float s  = vp - vn;
    v = vn;
    return s;
}

__device__ __forceinline__ float ubf(uint32_t w, int k) {
    return (float)((w >> (k * 8)) & 0xffu);
}

__device__ __forceinline__ float dot16(const float wr[16],
    float4 c0, float4 c1, float4 c2, float4 c3)
{
    float p0 = fmaf(wr[1], c0.y, wr[0] * c0.x);
    p0 = fmaf(wr[2], c0.z, p0);  p0 = fmaf(wr[3], c0.w, p0);
    float p1 = fmaf(wr[5], c1.y, wr[4] * c1.x);
    p1 = fmaf(wr[6], c1.z, p1);  p1 = fmaf(wr[7], c1.w, p1);
    float p2 = fmaf(wr[9], c2.y, wr[8] * c2.x);
    p2 = fmaf(wr[10], c2.z, p2); p2 = fmaf(wr[11], c2.w, p2);
    float p3 = fmaf(wr[13], c3.y, wr[12] * c3.x);
    p3 = fmaf(wr[14], c3.z, p3); p3 = fmaf(wr[15], c3.w, p3);
    return (p0 + p1) + (p2 + p3);
}

// R18 = R17 decomposition (thread owns 4 steps, computes all 16 channels from
// registers; NO x-LDS, NO chunk loop) with the R17 spill bug fixed:
//  * R17's __launch_bounds__(1024,4) capped VGPRs at 64 -> xr[16] (64 regs)
//    spilled to scratch: FETCH 160MB / WRITE 190MB of pure spill traffic.
//    Plain __launch_bounds__(1024) allows up to 128 VGPRs; LDS (131KB)
//    already pins occupancy at 1 block/CU = 4 waves/SIMD, so >64 regs is
//    FREE here.
//  * m1 cert dropped: m1 = max(acc+pw) <= m0 + alpha, so the sound bound
//    (1-vsu)*m0 + vsu*m1 relaxes to m0 + alpha*vsu (over-flag only; slack
//    <= (alpha-alpha^4)*vsu ~ 0.05 << margin to 0.999).  Kills pw/m1 regs
//    and ~800 VALU ops/thread; cert = float2{end, m0} fp32, no f16 encode.
//  * one_m premultiplied into weights (main + repair, consistent).
// Tails (scan2/scan3) stay fused and flag-gated (data produces no layer-1
// spikes: sigma~0.16 vs threshold 1).
__global__ __launch_bounds__(1024) void fused(
    const float* __restrict__ x, const float* __restrict__ w1,
    const float* __restrict__ w2, const float* __restrict__ w3,
    float* __restrict__ out, uint8_t* __restrict__ s1t,
    uint8_t* __restrict__ s2t,
    float alpha, float one_m, float alpha4)
{
    const int tid = threadIdx.x;
    const int b   = blockIdx.x;
    const int wv  = tid >> 6;
    const int ln  = tid & 63;

    __shared__ float2   sh_cert[16][EPITCH];        // 131.2 KiB: {end, m0}
    __shared__ uint32_t sh_badseg[16][NSEG / 32];   // 2 KiB
    __shared__ uint8_t  sh_bm1[NB_BLK];             // 256 B
    __shared__ uint8_t  sh_bm2[NB_BLK];             // 256 B
    __shared__ int      sh_badch, sh_spike, sh_flag2;

    const float* xb = x + (size_t)b * T_STEPS * 16;      // 65536 floats
    const float4* xq4 = (const float4*)xb;               // 16384 float4

    // ---- my 4 rows (= segment tid) straight into registers ----------------
    float4 xr[16];
#pragma unroll
    for (int q = 0; q < 16; ++q) xr[q] = xq4[tid * 16 + q];

    // ---- LDS flag/bitmap init ---------------------------------------------
    if (tid < 64)        ((uint32_t*)sh_bm1)[tid] = 0u;
    else if (tid < 128)  ((uint32_t*)sh_bm2)[tid - 64] = 0u;
    else if (tid == 128) { sh_badch = 0; sh_spike = 0; sh_flag2 = 0; }

    // ---- zero out[b] (overlaps x-load latency) ----------------------------
    float4* o4 = (float4*)(out + (size_t)b * T_STEPS * 10);   // 10240 float4
    float4 z4 = make_float4(0.f, 0.f, 0.f, 0.f);
#pragma unroll
    for (int i = 0; i < 10; ++i) o4[i * 1024 + tid] = z4;

    // ---- all 16 channels for my 4 steps; write cert summaries -------------
#pragma unroll 2
    for (int c = 0; c < 16; ++c) {
        float wc[16];
#pragma unroll
        for (int i = 0; i < 16; ++i) wc[i] = one_m * w1[c * 16 + i]; // uniform
        float acc = 0.0f, m0 = -1e30f;
#pragma unroll
        for (int j = 0; j < 4; ++j) {
            float y = dot16(wc, xr[j*4+0], xr[j*4+1], xr[j*4+2], xr[j*4+3]);
            acc = fmaf(alpha, acc, y);
            m0  = fmaxf(m0, acc);
        }
        sh_cert[c][tid] = make_float2(acc, m0);
    }
    __syncthreads();   // all cert entries visible

    // ---- composition + certification: 16 ch x 8 eighths (128 lanes) -------
    if (tid < 128) {
        const int c  = tid & 15;
        const int e8 = tid >> 4;
        const int s0 = e8 * 128;
        float vs = 0.0f;
        if (e8 > 0) {   // 40-seg warm-up: alpha4^40 = e^-8 = 3.4e-4 carry err
#pragma unroll 8
            for (int s = s0 - 40; s < s0; ++s)
                vs = fmaf(alpha4, vs, sh_cert[c][s].x);
        }
        uint32_t bw = 0;
        int bad = 0;
#pragma unroll 8
        for (int s = s0; s < s0 + 128; ++s) {
            float2 ct = sh_cert[c][s];
            float vsu = fminf(fmaxf(vs + 1e-3f, 0.0f), 1.0f);
            float bound = fmaf(alpha, vsu, ct.y);    // m0 + alpha*vsu (sound)
            if (!(bound < 0.999f)) { bw |= 1u << (s & 31); bad = 1; } // NaN->bad
            if ((s & 31) == 31) { sh_badseg[c][s >> 5] = bw; bw = 0; }
            vs = fmaf(alpha4, vs, ct.x);
        }
        if (bad) atomicOr(&sh_badch, 1 << c);
    }
    __syncthreads();

    // ---- parallel exact repair for cert-bad channels (rare) ---------------
    const int badmask = sh_badch;
    if (badmask) {
        // dense-zero s1t[b] so the scan2 phase never reads unwritten bytes
        uint4* sz = (uint4*)(s1t + (size_t)b * 16 * T_STEPS);
#pragma unroll
        for (int i = 0; i < 4; ++i) sz[i * 1024 + tid] = make_uint4(0u,0u,0u,0u);
        __syncthreads();   // zeroing ordered before repair spike writes

        int m = badmask;
        for (int i = 0; i < wv; ++i) m &= m - 1;
        if (ln == 0 && m) {
            const int c = __ffs(m) - 1;
            float wc[16];
#pragma unroll
            for (int i = 0; i < 16; ++i) wc[i] = one_m * w1[c * 16 + i];
            uint8_t* op = s1t + ((size_t)b * 16 + c) * T_STEPS;
            float v = 0.0f;
            int any = 0;
            for (int w32 = 0; w32 < 32; ++w32) {
                uint32_t bwv = sh_badseg[c][w32];
                const int sb = w32 * 32;
                if (bwv == 0u) {
#pragma unroll 8
                    for (int q = 0; q < 32; ++q)
                        v = fmaf(alpha4, v, sh_cert[c][sb + q].x);
                } else {
                    for (int q = 0; q < 32; ++q) {
                        const int s = sb + q;
                        if (!((bwv >> q) & 1u)) {
                            v = fmaf(alpha4, v, sh_cert[c][s].x);
                            continue;
                        }
                        const float4* xr2 = xq4 + (size_t)s * 16;
                        uint32_t sw = 0u;
#pragma unroll
                        for (int j = 0; j < 4; ++j) {
                            float y = dot16(wc, xr2[j*4+0], xr2[j*4+1],
                                                 xr2[j*4+2], xr2[j*4+3]);
                            float sp = lif_step(v, y, alpha);
                            sw |= ((uint32_t)(int)sp) << (j * 8);
                        }
                        if (sw) {
                            *(uint32_t*)(op + s * 4) = sw;
                            sh_bm1[s >> 2] = 1;
                            any = 1;
                        }
                    }
                }
            }
            if (any) sh_spike = 1;
        }
    }
    __syncthreads();   // orders repair writes + sh_spike/sh_bm1 for readers

    // ---- fused layer-2: sparse scan s1t -> s2t (+ sh_bm2) -----------------
    if (sh_spike) {
        if (tid < 32) {
            const int c2 = tid;
            float wr2[16];
#pragma unroll
            for (int i = 0; i < 16; ++i) wr2[i] = one_m * w2[c2 * 16 + i];
            const uint8_t* sb1 = s1t + (size_t)b * 16 * T_STEPS;
            uint4* op2 = (uint4*)(s2t + ((size_t)b * 32 + c2) * T_STEPS);
            const uint4* bmv = (const uint4*)sh_bm1;
            float v = 0.0f;
            for (int sb = 0; sb < 16; ++sb) {
                uint4 bm = bmv[sb];
                if ((bm.x | bm.y | bm.z | bm.w) == 0u) {
                    if (v != 0.0f) {
                        for (int blk = 0; blk < 16 && v != 0.0f; ++blk) {
#pragma unroll
                            for (int j = 0; j < 16; ++j) v *= alpha;
                        }
                    }
                    continue;
                }
                for (int blk = 0; blk < 16; ++blk) {
                    uint32_t d = (blk < 4) ? bm.x : (blk < 8) ? bm.y
                               : (blk < 12) ? bm.z : bm.w;
                    uint32_t byte = (d >> ((blk & 3) * 8)) & 0xffu;
                    if (byte == 0u) {
                        if (v != 0.0f) {
#pragma unroll
                            for (int j = 0; j < 16; ++j) v *= alpha;
                        }
                        continue;
                    }
                    const int tb = sb * 16 + blk;
                    const int t0 = tb * 16;
                    uint4 S[16];
#pragma unroll
                    for (int c = 0; c < 16; ++c)
                        S[c] = *(const uint4*)(sb1 + (size_t)c * T_STEPS + t0);
                    uint32_t w[4] = {0u, 0u, 0u, 0u};
#pragma unroll
                    for (int j = 0; j < 16; ++j) {
                        float xv[16];
#pragma unroll
                        for (int c = 0; c < 16; ++c) {
                            uint32_t dd = (j < 4) ? S[c].x : (j < 8) ? S[c].y
                                        : (j < 12) ? S[c].z : S[c].w;
                            xv[c] = ubf(dd, j & 3);
                        }
                        float p0 = fmaf(wr2[1], xv[1], wr2[0] * xv[0]);
                        p0 = fmaf(wr2[2], xv[2], p0);   p0 = fmaf(wr2[3], xv[3], p0);
                        float p1 = fmaf(wr2[5], xv[5], wr2[4] * xv[4]);
                        p1 = fmaf(wr2[6], xv[6], p1);   p1 = fmaf(wr2[7], xv[7], p1);
                        float p2 = fmaf(wr2[9], xv[9], wr2[8] * xv[8]);
                        p2 = fmaf(wr2[10], xv[10], p2); p2 = fmaf(wr2[11], xv[11], p2);
                        float p3 = fmaf(wr2[13], xv[13], wr2[12] * xv[12]);
                        p3 = fmaf(wr2[14], xv[14], p3); p3 = fmaf(wr2[15], xv[15], p3);
                        float xs = (p0 + p1) + (p2 + p3);
                        float s = lif_step(v, xs, alpha);
                        w[j >> 2] |= ((uint32_t)(int)s) << ((j & 3) * 8);
                    }
                    op2[tb] = make_uint4(w[0], w[1], w[2], w[3]);
                    if (w[0] | w[1] | w[2] | w[3]) { sh_bm2[tb] = 1; sh_flag2 = 1; }
                }
            }
        }
        __syncthreads();   // s2t/sh_bm2/sh_flag2 visible

        // ---- fused layer-3: sparse scan s2t -> out (pre-zeroed) -----------
        if (sh_flag2 && tid < 16) {
            const int c3 = tid;
            const bool active = (c3 < 10);
            float wr3[32];
#pragma unroll
            for (int i = 0; i < 32; ++i)
                wr3[i] = active ? (one_m * w3[c3 * 32 + i]) : 0.0f;
            const uint8_t* sb2 = s2t + (size_t)b * 32 * T_STEPS;
            const uint4* bmv2 = (const uint4*)sh_bm2;
            float* ob = out + (size_t)b * T_STEPS * 10 + c3;
            float v = 0.0f;
            for (int sb = 0; sb < 16; ++sb) {
                uint4 bm = bmv2[sb];
                if ((bm.x | bm.y | bm.z | bm.w) == 0u) {
                    if (v != 0.0f) {
                        for (int blk = 0; blk < 16 && v != 0.0f; ++blk) {
#pragma unroll
                            for (int j = 0; j < 16; ++j) v *= alpha;
                        }
                    }
                    continue;
                }
                for (int blk = 0; blk < 16; ++blk) {
                    uint32_t d = (blk < 4) ? bm.x : (blk < 8) ? bm.y
                               : (blk < 12) ? bm.z : bm.w;
                    uint32_t byte = (d >> ((blk & 3) * 8)) & 0xffu;
                    if (byte == 0u) {
                        if (v != 0.0f) {
#pragma unroll
                            for (int j = 0; j < 16; ++j) v *= alpha;
                        }
                        continue;
                    }
                    const int t0 = (sb * 16 + blk) * 16;
                    uint4 S[32];
#pragma unroll
                    for (int c = 0; c < 32; ++c)
                        S[c] = *(const uint4*)(sb2 + (size_t)c * T_STEPS + t0);
#pragma unroll
                    for (int j = 0; j < 16; ++j) {
                        float xv[32];
#pragma unroll
                        for (int c = 0; c < 32; ++c) {
                            uint32_t dd = (j < 4) ? S[c].x : (j < 8) ? S[c].y
                                        : (j < 12) ? S[c].z : S[c].w;
                            xv[c] = ubf(dd, j & 3);
                        }
                        float p0 = fmaf(wr3[1], xv[1], wr3[0] * xv[0]);
                        p0 = fmaf(wr3[2],  xv[2],  p0); p0 = fmaf(wr3[3],  xv[3],  p0);
                        p0 = fmaf(wr3[4],  xv[4],  p0); p0 = fmaf(wr3[5],  xv[5],  p0);
                        p0 = fmaf(wr3[6],  xv[6],  p0); p0 = fmaf(wr3[7],  xv[7],  p0);
                        float p1 = fmaf(wr3[9], xv[9], wr3[8] * xv[8]);
                        p1 = fmaf(wr3[10], xv[10], p1); p1 = fmaf(wr3[11], xv[11], p1);
                        p1 = fmaf(wr3[12], xv[12], p1); p1 = fmaf(wr3[13], xv[13], p1);
                        p1 = fmaf(wr3[14], xv[14], p1); p1 = fmaf(wr3[15], xv[15], p1);
                        float p2 = fmaf(wr3[17], xv[17], wr3[16] * xv[16]);
                        p2 = fmaf(wr3[18], xv[18], p2); p2 = fmaf(wr3[19], xv[19], p2);
                        p2 = fmaf(wr3[20], xv[20], p2); p2 = fmaf(wr3[21], xv[21], p2);
                        p2 = fmaf(wr3[22], xv[22], p2); p2 = fmaf(wr3[23], xv[23], p2);
                        float p3 = fmaf(wr3[25], xv[25], wr3[24] * xv[24]);
                        p3 = fmaf(wr3[26], xv[26], p3); p3 = fmaf(wr3[27], xv[27], p3);
                        p3 = fmaf(wr3[28], xv[28], p3); p3 = fmaf(wr3[29], xv[29], p3);
                        p3 = fmaf(wr3[30], xv[30], p3); p3 = fmaf(wr3[31], xv[31], p3);
                        float xs = (p0 + p1) + (p2 + p3);
                        float s = lif_step(v, xs, alpha);
                        if (active && s != 0.0f) ob[(size_t)(t0 + j) * 10] = s;
                    }
                }
            }
        }
    }
}

extern "C" void kernel_launch(void* const* d_in, const int* in_sizes, int n_in,
                              void* d_out, int out_size, void* d_ws, size_t ws_size,
                              hipStream_t stream)
{
    const float* data = (const float*)d_in[0];
    const float* w1   = (const float*)d_in[1];
    const float* w2   = (const float*)d_in[2];
    const float* w3   = (const float*)d_in[3];
    float* out = (float*)d_out;

    // ws layout (48 MiB):
    //   [0, 16M)    s1t  u8 [256][16][4096]  (dense-zeroed only for bad b)
    //   [16M, 48M)  s2t  u8 [256][32][4096]  (sparse: only bm2-set blocks valid)
    uint8_t* ws  = (uint8_t*)d_ws;
    uint8_t* s1t = ws;
    uint8_t* s2t = ws + (16u << 20);

    const float alpha  = expf(-1.0f / 20.0f);
    const float one_m  = 1.0f - alpha;
    const float alpha4 = expf(-4.0f / 20.0f);

    fused<<<BATCH, 1024, 0, stream>>>(data, w1, w2, w3, out, s1t, s2t,
                                      alpha, one_m, alpha4);
}

// Round 6
// 222.676 us; speedup vs baseline: 1.0986x; 1.0252x over previous
//
#include <hip/hip_runtime.h>
#include <stdint.h>
#include <math.h>

#define T_STEPS 4096
#define BATCH   256
#define NB_BLK  256      // 16-step spike blocks (scan2/3 bitmap granularity)
#define NSEG    1024     // 4-step cert segments per batch
#define EPITCH  1025     // [c][seg] pitch in float2 units (bank spread)

// LIF step, threshold=1:  v'=alpha*v+xs; s=max(floor(v'),0); v=v'-s
// Identity: v_new = min(v', fract(v')); s = v' - v_new (exact fp32).
__device__ __forceinline__ float lif_step(float& v, float xs, float alpha) {
    float vp = fmaf(alpha, v, xs);
    float fr = vp - floorf(vp);
    float vn = fminf(vp, fr);
    float s  = vp - vn;
    v = vn;
    return s;
}

__device__ __forceinline__ float ubf(uint32_t w, int k) {
    return (float)((w >> (k * 8)) & 0xffu);
}

__device__ __forceinline__ float dot16(const float wr[16],
    float4 c0, float4 c1, float4 c2, float4 c3)
{
    float p0 = fmaf(wr[1], c0.y, wr[0] * c0.x);
    p0 = fmaf(wr[2], c0.z, p0);  p0 = fmaf(wr[3], c0.w, p0);
    float p1 = fmaf(wr[5], c1.y, wr[4] * c1.x);
    p1 = fmaf(wr[6], c1.z, p1);  p1 = fmaf(wr[7], c1.w, p1);
    float p2 = fmaf(wr[9], c2.y, wr[8] * c2.x);
    p2 = fmaf(wr[10], c2.z, p2); p2 = fmaf(wr[11], c2.w, p2);
    float p3 = fmaf(wr[13], c3.y, wr[12] * c3.x);
    p3 = fmaf(wr[14], c3.z, p3); p3 = fmaf(wr[15], c3.w, p3);
    return (p0 + p1) + (p2 + p3);
}

// R19 = R18 with the register-cap/pressure bug actually fixed:
//  * R17 (launch_bounds(1024,4)) and R18 (launch_bounds(1024)) BOTH compiled
//    to VGPR_Count=64 (compiler default targets ~8 waves/EU) while the live
//    set was ~112 (xr[16]=64 + VALU-premultiplied wc[16]=16 + acc/temps) ->
//    ~48 regs spilled to scratch: 130MB extra FETCH + 77MB extra WRITE.
//  * Fix 1: amdgpu_waves_per_eu(1,4).  131KB LDS pins 1 block/CU = 4
//    waves/EU, so max=4 legitimately raises the VGPR cap to 512/4 = 128.
//  * Fix 2: weights stay in SGPRs: wc[i] = w1[c*16+i] raw (uniform s_load),
//    one_m applied once per dot product (one_m*y) in main AND repair.
//    Live VGPRs ~80 < 128 -> no spill.
//  * unroll 2 on the c-loop keeps only 2 channels' weights (32 SGPR) live.
// Everything else identical to R18 (thread owns 4 steps / computes all 16
// channels from registers; cert {end,m0} fp32; m0 + alpha*vsu sound bound;
// 16ch x 8 eighths composition with 40-seg warm-up; parallel repair; fused
// flag-gated scan2/scan3 tails).
__global__ __launch_bounds__(1024)
__attribute__((amdgpu_waves_per_eu(1, 4)))
void fused(
    const float* __restrict__ x, const float* __restrict__ w1,
    const float* __restrict__ w2, const float* __restrict__ w3,
    float* __restrict__ out, uint8_t* __restrict__ s1t,
    uint8_t* __restrict__ s2t,
    float alpha, float one_m, float alpha4)
{
    const int tid = threadIdx.x;
    const int b   = blockIdx.x;
    const int wv  = tid >> 6;
    const int ln  = tid & 63;

    __shared__ float2   sh_cert[16][EPITCH];        // 131.2 KiB: {end, m0}
    __shared__ uint32_t sh_badseg[16][NSEG / 32];   // 2 KiB
    __shared__ uint8_t  sh_bm1[NB_BLK];             // 256 B
    __shared__ uint8_t  sh_bm2[NB_BLK];             // 256 B
    __shared__ int      sh_badch, sh_spike, sh_flag2;

    const float* xb = x + (size_t)b * T_STEPS * 16;      // 65536 floats
    const float4* xq4 = (const float4*)xb;               // 16384 float4

    // ---- my 4 rows (= segment tid) straight into registers ----------------
    float4 xr[16];
#pragma unroll
    for (int q = 0; q < 16; ++q) xr[q] = xq4[tid * 16 + q];

    // ---- LDS flag/bitmap init ---------------------------------------------
    if (tid < 64)        ((uint32_t*)sh_bm1)[tid] = 0u;
    else if (tid < 128)  ((uint32_t*)sh_bm2)[tid - 64] = 0u;
    else if (tid == 128) { sh_badch = 0; sh_spike = 0; sh_flag2 = 0; }

    // ---- zero out[b] (overlaps x-load latency) ----------------------------
    float4* o4 = (float4*)(out + (size_t)b * T_STEPS * 10);   // 10240 float4
    float4 z4 = make_float4(0.f, 0.f, 0.f, 0.f);
#pragma unroll
    for (int i = 0; i < 10; ++i) o4[i * 1024 + tid] = z4;

    // ---- all 16 channels for my 4 steps; write cert summaries -------------
#pragma unroll 2
    for (int c = 0; c < 16; ++c) {
        float wc[16];
#pragma unroll
        for (int i = 0; i < 16; ++i) wc[i] = w1[c * 16 + i];   // uniform->SGPR
        float acc = 0.0f, m0 = -1e30f;
#pragma unroll
        for (int j = 0; j < 4; ++j) {
            float y = dot16(wc, xr[j*4+0], xr[j*4+1], xr[j*4+2], xr[j*4+3]);
            acc = fmaf(alpha, acc, one_m * y);
            m0  = fmaxf(m0, acc);
        }
        sh_cert[c][tid] = make_float2(acc, m0);
    }
    __syncthreads();   // all cert entries visible

    // ---- composition + certification: 16 ch x 8 eighths (128 lanes) -------
    if (tid < 128) {
        const int c  = tid & 15;
        const int e8 = tid >> 4;
        const int s0 = e8 * 128;
        float vs = 0.0f;
        if (e8 > 0) {   // 40-seg warm-up: alpha4^40 = e^-8 = 3.4e-4 carry err
#pragma unroll 8
            for (int s = s0 - 40; s < s0; ++s)
                vs = fmaf(alpha4, vs, sh_cert[c][s].x);
        }
        uint32_t bw = 0;
        int bad = 0;
#pragma unroll 8
        for (int s = s0; s < s0 + 128; ++s) {
            float2 ct = sh_cert[c][s];
            float vsu = fminf(fmaxf(vs + 1e-3f, 0.0f), 1.0f);
            float bound = fmaf(alpha, vsu, ct.y);    // m0 + alpha*vsu (sound)
            if (!(bound < 0.999f)) { bw |= 1u << (s & 31); bad = 1; } // NaN->bad
            if ((s & 31) == 31) { sh_badseg[c][s >> 5] = bw; bw = 0; }
            vs = fmaf(alpha4, vs, ct.x);
        }
        if (bad) atomicOr(&sh_badch, 1 << c);
    }
    __syncthreads();

    // ---- parallel exact repair for cert-bad channels (rare) ---------------
    const int badmask = sh_badch;
    if (badmask) {
        // dense-zero s1t[b] so the scan2 phase never reads unwritten bytes
        uint4* sz = (uint4*)(s1t + (size_t)b * 16 * T_STEPS);
#pragma unroll
        for (int i = 0; i < 4; ++i) sz[i * 1024 + tid] = make_uint4(0u,0u,0u,0u);
        __syncthreads();   // zeroing ordered before repair spike writes

        int m = badmask;
        for (int i = 0; i < wv; ++i) m &= m - 1;
        if (ln == 0 && m) {
            const int c = __ffs(m) - 1;
            float wc[16];
#pragma unroll
            for (int i = 0; i < 16; ++i) wc[i] = w1[c * 16 + i];
            uint8_t* op = s1t + ((size_t)b * 16 + c) * T_STEPS;
            float v = 0.0f;
            int any = 0;
            for (int w32 = 0; w32 < 32; ++w32) {
                uint32_t bwv = sh_badseg[c][w32];
                const int sb = w32 * 32;
                if (bwv == 0u) {
#pragma unroll 8
                    for (int q = 0; q < 32; ++q)
                        v = fmaf(alpha4, v, sh_cert[c][sb + q].x);
                } else {
                    for (int q = 0; q < 32; ++q) {
                        const int s = sb + q;
                        if (!((bwv >> q) & 1u)) {
                            v = fmaf(alpha4, v, sh_cert[c][s].x);
                            continue;
                        }
                        const float4* xr2 = xq4 + (size_t)s * 16;
                        uint32_t sw = 0u;
#pragma unroll
                        for (int j = 0; j < 4; ++j) {
                            float y = dot16(wc, xr2[j*4+0], xr2[j*4+1],
                                                 xr2[j*4+2], xr2[j*4+3]);
                            float sp = lif_step(v, one_m * y, alpha);
                            sw |= ((uint32_t)(int)sp) << (j * 8);
                        }
                        if (sw) {
                            *(uint32_t*)(op + s * 4) = sw;
                            sh_bm1[s >> 2] = 1;
                            any = 1;
                        }
                    }
                }
            }
            if (any) sh_spike = 1;
        }
    }
    __syncthreads();   // orders repair writes + sh_spike/sh_bm1 for readers

    // ---- fused layer-2: sparse scan s1t -> s2t (+ sh_bm2) -----------------
    if (sh_spike) {
        if (tid < 32) {
            const int c2 = tid;
            float wr2[16];
#pragma unroll
            for (int i = 0; i < 16; ++i) wr2[i] = one_m * w2[c2 * 16 + i];
            const uint8_t* sb1 = s1t + (size_t)b * 16 * T_STEPS;
            uint4* op2 = (uint4*)(s2t + ((size_t)b * 32 + c2) * T_STEPS);
            const uint4* bmv = (const uint4*)sh_bm1;
            float v = 0.0f;
            for (int sb = 0; sb < 16; ++sb) {
                uint4 bm = bmv[sb];
                if ((bm.x | bm.y | bm.z | bm.w) == 0u) {
                    if (v != 0.0f) {
                        for (int blk = 0; blk < 16 && v != 0.0f; ++blk) {
#pragma unroll
                            for (int j = 0; j < 16; ++j) v *= alpha;
                        }
                    }
                    continue;
                }
                for (int blk = 0; blk < 16; ++blk) {
                    uint32_t d = (blk < 4) ? bm.x : (blk < 8) ? bm.y
                               : (blk < 12) ? bm.z : bm.w;
                    uint32_t byte = (d >> ((blk & 3) * 8)) & 0xffu;
                    if (byte == 0u) {
                        if (v != 0.0f) {
#pragma unroll
                            for (int j = 0; j < 16; ++j) v *= alpha;
                        }
                        continue;
                    }
                    const int tb = sb * 16 + blk;
                    const int t0 = tb * 16;
                    uint4 S[16];
#pragma unroll
                    for (int c = 0; c < 16; ++c)
                        S[c] = *(const uint4*)(sb1 + (size_t)c * T_STEPS + t0);
                    uint32_t w[4] = {0u, 0u, 0u, 0u};
#pragma unroll
                    for (int j = 0; j < 16; ++j) {
                        float xv[16];
#pragma unroll
                        for (int c = 0; c < 16; ++c) {
                            uint32_t dd = (j < 4) ? S[c].x : (j < 8) ? S[c].y
                                        : (j < 12) ? S[c].z : S[c].w;
                            xv[c] = ubf(dd, j & 3);
                        }
                        float p0 = fmaf(wr2[1], xv[1], wr2[0] * xv[0]);
                        p0 = fmaf(wr2[2], xv[2], p0);   p0 = fmaf(wr2[3], xv[3], p0);
                        float p1 = fmaf(wr2[5], xv[5], wr2[4] * xv[4]);
                        p1 = fmaf(wr2[6], xv[6], p1);   p1 = fmaf(wr2[7], xv[7], p1);
                        float p2 = fmaf(wr2[9], xv[9], wr2[8] * xv[8]);
                        p2 = fmaf(wr2[10], xv[10], p2); p2 = fmaf(wr2[11], xv[11], p2);
                        float p3 = fmaf(wr2[13], xv[13], wr2[12] * xv[12]);
                        p3 = fmaf(wr2[14], xv[14], p3); p3 = fmaf(wr2[15], xv[15], p3);
                        float xs = (p0 + p1) + (p2 + p3);
                        float s = lif_step(v, xs, alpha);
                        w[j >> 2] |= ((uint32_t)(int)s) << ((j & 3) * 8);
                    }
                    op2[tb] = make_uint4(w[0], w[1], w[2], w[3]);
                    if (w[0] | w[1] | w[2] | w[3]) { sh_bm2[tb] = 1; sh_flag2 = 1; }
                }
            }
        }
        __syncthreads();   // s2t/sh_bm2/sh_flag2 visible

        // ---- fused layer-3: sparse scan s2t -> out (pre-zeroed) -----------
        if (sh_flag2 && tid < 16) {
            const int c3 = tid;
            const bool active = (c3 < 10);
            float wr3[32];
#pragma unroll
            for (int i = 0; i < 32; ++i)
                wr3[i] = active ? (one_m * w3[c3 * 32 + i]) : 0.0f;
            const uint8_t* sb2 = s2t + (size_t)b * 32 * T_STEPS;
            const uint4* bmv2 = (const uint4*)sh_bm2;
            float* ob = out + (size_t)b * T_STEPS * 10 + c3;
            float v = 0.0f;
            for (int sb = 0; sb < 16; ++sb) {
                uint4 bm = bmv2[sb];
                if ((bm.x | bm.y | bm.z | bm.w) == 0u) {
                    if (v != 0.0f) {
                        for (int blk = 0; blk < 16 && v != 0.0f; ++blk) {
#pragma unroll
                            for (int j = 0; j < 16; ++j) v *= alpha;
                        }
                    }
                    continue;
                }
                for (int blk = 0; blk < 16; ++blk) {
                    uint32_t d = (blk < 4) ? bm.x : (blk < 8) ? bm.y
                               : (blk < 12) ? bm.z : bm.w;
                    uint32_t byte = (d >> ((blk & 3) * 8)) & 0xffu;
                    if (byte == 0u) {
                        if (v != 0.0f) {
#pragma unroll
                            for (int j = 0; j < 16; ++j) v *= alpha;
                        }
                        continue;
                    }
                    const int t0 = (sb * 16 + blk) * 16;
                    uint4 S[32];
#pragma unroll
                    for (int c = 0; c < 32; ++c)
                        S[c] = *(const uint4*)(sb2 + (size_t)c * T_STEPS + t0);
#pragma unroll
                    for (int j = 0; j < 16; ++j) {
                        float xv[32];
#pragma unroll
                        for (int c = 0; c < 32; ++c) {
                            uint32_t dd = (j < 4) ? S[c].x : (j < 8) ? S[c].y
                                        : (j < 12) ? S[c].z : S[c].w;
                            xv[c] = ubf(dd, j & 3);
                        }
                        float p0 = fmaf(wr3[1], xv[1], wr3[0] * xv[0]);
                        p0 = fmaf(wr3[2],  xv[2],  p0); p0 = fmaf(wr3[3],  xv[3],  p0);
                        p0 = fmaf(wr3[4],  xv[4],  p0); p0 = fmaf(wr3[5],  xv[5],  p0);
                        p0 = fmaf(wr3[6],  xv[6],  p0); p0 = fmaf(wr3[7],  xv[7],  p0);
                        float p1 = fmaf(wr3[9], xv[9], wr3[8] * xv[8]);
                        p1 = fmaf(wr3[10], xv[10], p1); p1 = fmaf(wr3[11], xv[11], p1);
                        p1 = fmaf(wr3[12], xv[12], p1); p1 = fmaf(wr3[13], xv[13], p1);
                        p1 = fmaf(wr3[14], xv[14], p1); p1 = fmaf(wr3[15], xv[15], p1);
                        float p2 = fmaf(wr3[17], xv[17], wr3[16] * xv[16]);
                        p2 = fmaf(wr3[18], xv[18], p2); p2 = fmaf(wr3[19], xv[19], p2);
                        p2 = fmaf(wr3[20], xv[20], p2); p2 = fmaf(wr3[21], xv[21], p2);
                        p2 = fmaf(wr3[22], xv[22], p2); p2 = fmaf(wr3[23], xv[23], p2);
                        float p3 = fmaf(wr3[25], xv[25], wr3[24] * xv[24]);
                        p3 = fmaf(wr3[26], xv[26], p3); p3 = fmaf(wr3[27], xv[27], p3);
                        p3 = fmaf(wr3[28], xv[28], p3); p3 = fmaf(wr3[29], xv[29], p3);
                        p3 = fmaf(wr3[30], xv[30], p3); p3 = fmaf(wr3[31], xv[31], p3);
                        float xs = (p0 + p1) + (p2 + p3);
                        float s = lif_step(v, xs, alpha);
                        if (active && s != 0.0f) ob[(size_t)(t0 + j) * 10] = s;
                    }
                }
            }
        }
    }
}

extern "C" void kernel_launch(void* const* d_in, const int* in_sizes, int n_in,
                              void* d_out, int out_size, void* d_ws, size_t ws_size,
                              hipStream_t stream)
{
    const float* data = (const float*)d_in[0];
    const float* w1   = (const float*)d_in[1];
    const float* w2   = (const float*)d_in[2];
    const float* w3   = (const float*)d_in[3];
    float* out = (float*)d_out;

    // ws layout (48 MiB):
    //   [0, 16M)    s1t  u8 [256][16][4096]  (dense-zeroed only for bad b)
    //   [16M, 48M)  s2t  u8 [256][32][4096]  (sparse: only bm2-set blocks valid)
    uint8_t* ws  = (uint8_t*)d_ws;
    uint8_t* s1t = ws;
    uint8_t* s2t = ws + (16u << 20);

    const float alpha  = expf(-1.0f / 20.0f);
    const float one_m  = 1.0f - alpha;
    const float alpha4 = expf(-4.0f / 20.0f);

    fused<<<BATCH, 1024, 0, stream>>>(data, w1, w2, w3, out, s1t, s2t,
                                      alpha, one_m, alpha4);
}

// Round 7
// 150.088 us; speedup vs baseline: 1.6300x; 1.4836x over previous
//
#include <hip/hip_runtime.h>
#include <stdint.h>
#include <math.h>

#define T_STEPS 4096
#define BATCH   256
#define NB_BLK  256      // 16-step spike blocks (scan2/3 bitmap granularity)
#define NSEG    1024     // 4-step cert segments per batch
#define EPITCH  1025     // [c][seg] pitch in float2 units (bank spread)

// LIF step, threshold=1:  v'=alpha*v+xs; s=max(floor(v'),0); v=v'-s
// Identity: v_new = min(v', fract(v')); s = v' - v_new (exact fp32).
__device__ __forceinline__ float lif_step(float& v, float xs, float alpha) {
    float vp = fmaf(alpha, v, xs);
    float fr = vp - floorf(vp);
    float vn = fminf(vp, fr);
    float s  = vp - vn;
    v = vn;
    return s;
}

__device__ __forceinline__ float ubf(uint32_t w, int k) {
    return (float)((w >> (k * 8)) & 0xffu);
}

// force a uniform value into an SGPR (weights): keeps VGPR live-set small
__device__ __forceinline__ float sgpr_f(float v) {
    return __uint_as_float(__builtin_amdgcn_readfirstlane(__float_as_uint(v)));
}

__device__ __forceinline__ float dot16(const float wr[16],
    float4 c0, float4 c1, float4 c2, float4 c3)
{
    float p0 = fmaf(wr[1], c0.y, wr[0] * c0.x);
    p0 = fmaf(wr[2], c0.z, p0);  p0 = fmaf(wr[3], c0.w, p0);
    float p1 = fmaf(wr[5], c1.y, wr[4] * c1.x);
    p1 = fmaf(wr[6], c1.z, p1);  p1 = fmaf(wr[7], c1.w, p1);
    float p2 = fmaf(wr[9], c2.y, wr[8] * c2.x);
    p2 = fmaf(wr[10], c2.z, p2); p2 = fmaf(wr[11], c2.w, p2);
    float p3 = fmaf(wr[13], c3.y, wr[12] * c3.x);
    p3 = fmaf(wr[14], c3.z, p3); p3 = fmaf(wr[15], c3.w, p3);
    return (p0 + p1) + (p2 + p3);
}

// R20: two-pass main compute to fit the 64-VGPR cap the compiler insists on.
// Evidence: R17/R18/R19 all compiled to VGPR_Count=64 regardless of
// launch_bounds / waves_per_eu hints, and xr[16] (64 regs) alone filled the
// file -> ~50 regs of scratch spill = 60-140MB extra HBM traffic each way.
// Fix: thread still owns its 4-step segment, but processes it as TWO 2-step
// passes (xr[8] = 32 regs live), combining partials IN PLACE in sh_cert:
//   pass A: accA = 2-step zero-state sum, m0A = max membrane  -> sh_cert
//   pass B: standalone accB/m0B; end = alpha^2*accA + accB (exact to ~1e-7,
//           inside the 1e-3 jump guard band); m0 = max(m0A, m0B +
//           alpha*relu(accA))  [alpha^j <= alpha for j>=1 -> sound upper
//           bound, over-flags only].
// Same-thread LDS read-after-write is wave-ordered -> no barrier between
// passes.  Weights forced to SGPR via readfirstlane (uniform).  Peak live
// VGPRs ~45 < 64 -> no spill.  Everything else identical to R19: cert
// {end,m0} fp32, bound = m0 + alpha*vsu, 16ch x 8 eighths composition with
// 40-seg warm-up, parallel per-wave repair, fused flag-gated scan2/scan3.
__global__ __launch_bounds__(1024) void fused(
    const float* __restrict__ x, const float* __restrict__ w1,
    const float* __restrict__ w2, const float* __restrict__ w3,
    float* __restrict__ out, uint8_t* __restrict__ s1t,
    uint8_t* __restrict__ s2t,
    float alpha, float one_m, float alpha4)
{
    const int tid = threadIdx.x;
    const int b   = blockIdx.x;
    const int wv  = tid >> 6;
    const int ln  = tid & 63;

    __shared__ float2   sh_cert[16][EPITCH];        // 131.2 KiB: {end, m0}
    __shared__ uint32_t sh_badseg[16][NSEG / 32];   // 2 KiB
    __shared__ uint8_t  sh_bm1[NB_BLK];             // 256 B
    __shared__ uint8_t  sh_bm2[NB_BLK];             // 256 B
    __shared__ int      sh_badch, sh_spike, sh_flag2;

    const float* xb = x + (size_t)b * T_STEPS * 16;      // 65536 floats
    const float4* xq4 = (const float4*)xb;               // 16384 float4

    // ---- LDS flag/bitmap init ---------------------------------------------
    if (tid < 64)        ((uint32_t*)sh_bm1)[tid] = 0u;
    else if (tid < 128)  ((uint32_t*)sh_bm2)[tid - 64] = 0u;
    else if (tid == 128) { sh_badch = 0; sh_spike = 0; sh_flag2 = 0; }

    // ---- zero out[b] (overlaps x-load latency) ----------------------------
    float4* o4 = (float4*)(out + (size_t)b * T_STEPS * 10);   // 10240 float4
    float4 z4 = make_float4(0.f, 0.f, 0.f, 0.f);
#pragma unroll
    for (int i = 0; i < 10; ++i) o4[i * 1024 + tid] = z4;

    const float alpha2 = alpha * alpha;

    // ---- pass A: steps 0-1 of my segment (rows 0-1, 128B) -----------------
    {
        float4 xr[8];
#pragma unroll
        for (int q = 0; q < 8; ++q) xr[q] = xq4[tid * 16 + q];
#pragma unroll 2
        for (int c = 0; c < 16; ++c) {
            float wc[16];
#pragma unroll
            for (int i = 0; i < 16; ++i) wc[i] = sgpr_f(w1[c * 16 + i]);
            float y0 = dot16(wc, xr[0], xr[1], xr[2], xr[3]);
            float y1 = dot16(wc, xr[4], xr[5], xr[6], xr[7]);
            float a0 = one_m * y0;
            float a1 = fmaf(alpha, a0, one_m * y1);
            sh_cert[c][tid] = make_float2(a1, fmaxf(a0, a1));
        }
    }
    // ---- pass B: steps 2-3 (rows 2-3); combine in place (wave-ordered DS) -
    {
        float4 xr[8];
#pragma unroll
        for (int q = 0; q < 8; ++q) xr[q] = xq4[tid * 16 + 8 + q];
#pragma unroll 2
        for (int c = 0; c < 16; ++c) {
            float wc[16];
#pragma unroll
            for (int i = 0; i < 16; ++i) wc[i] = sgpr_f(w1[c * 16 + i]);
            float y2 = dot16(wc, xr[0], xr[1], xr[2], xr[3]);
            float y3 = dot16(wc, xr[4], xr[5], xr[6], xr[7]);
            float b0 = one_m * y2;
            float b1 = fmaf(alpha, b0, one_m * y3);
            float mB = fmaxf(b0, b1);
            float2 ca = sh_cert[c][tid];
            float end = fmaf(alpha2, ca.x, b1);
            float m0  = fmaxf(ca.y, fmaf(alpha, fmaxf(ca.x, 0.0f), mB));
            sh_cert[c][tid] = make_float2(end, m0);
        }
    }
    __syncthreads();   // all cert entries visible

    // ---- composition + certification: 16 ch x 8 eighths (128 lanes) -------
    if (tid < 128) {
        const int c  = tid & 15;
        const int e8 = tid >> 4;
        const int s0 = e8 * 128;
        float vs = 0.0f;
        if (e8 > 0) {   // 40-seg warm-up: alpha4^40 = e^-8 = 3.4e-4 carry err
#pragma unroll 8
            for (int s = s0 - 40; s < s0; ++s)
                vs = fmaf(alpha4, vs, sh_cert[c][s].x);
        }
        uint32_t bw = 0;
        int bad = 0;
#pragma unroll 8
        for (int s = s0; s < s0 + 128; ++s) {
            float2 ct = sh_cert[c][s];
            float vsu = fminf(fmaxf(vs + 1e-3f, 0.0f), 1.0f);
            float bound = fmaf(alpha, vsu, ct.y);    // m0 + alpha*vsu (sound)
            if (!(bound < 0.999f)) { bw |= 1u << (s & 31); bad = 1; } // NaN->bad
            if ((s & 31) == 31) { sh_badseg[c][s >> 5] = bw; bw = 0; }
            vs = fmaf(alpha4, vs, ct.x);
        }
        if (bad) atomicOr(&sh_badch, 1 << c);
    }
    __syncthreads();

    // ---- parallel exact repair for cert-bad channels (rare) ---------------
    const int badmask = sh_badch;
    if (badmask) {
        // dense-zero s1t[b] so the scan2 phase never reads unwritten bytes
        uint4* sz = (uint4*)(s1t + (size_t)b * 16 * T_STEPS);
#pragma unroll
        for (int i = 0; i < 4; ++i) sz[i * 1024 + tid] = make_uint4(0u,0u,0u,0u);
        __syncthreads();   // zeroing ordered before repair spike writes

        int m = badmask;
        for (int i = 0; i < wv; ++i) m &= m - 1;
        if (ln == 0 && m) {
            const int c = __ffs(m) - 1;
            float wc[16];
#pragma unroll
            for (int i = 0; i < 16; ++i) wc[i] = w1[c * 16 + i];
            uint8_t* op = s1t + ((size_t)b * 16 + c) * T_STEPS;
            float v = 0.0f;
            int any = 0;
            for (int w32 = 0; w32 < 32; ++w32) {
                uint32_t bwv = sh_badseg[c][w32];
                const int sb = w32 * 32;
                if (bwv == 0u) {
#pragma unroll 8
                    for (int q = 0; q < 32; ++q)
                        v = fmaf(alpha4, v, sh_cert[c][sb + q].x);
                } else {
                    for (int q = 0; q < 32; ++q) {
                        const int s = sb + q;
                        if (!((bwv >> q) & 1u)) {
                            v = fmaf(alpha4, v, sh_cert[c][s].x);
                            continue;
                        }
                        const float4* xr2 = xq4 + (size_t)s * 16;
                        uint32_t sw = 0u;
#pragma unroll
                        for (int j = 0; j < 4; ++j) {
                            float y = dot16(wc, xr2[j*4+0], xr2[j*4+1],
                                                 xr2[j*4+2], xr2[j*4+3]);
                            float sp = lif_step(v, one_m * y, alpha);
                            sw |= ((uint32_t)(int)sp) << (j * 8);
                        }
                        if (sw) {
                            *(uint32_t*)(op + s * 4) = sw;
                            sh_bm1[s >> 2] = 1;
                            any = 1;
                        }
                    }
                }
            }
            if (any) sh_spike = 1;
        }
    }
    __syncthreads();   // orders repair writes + sh_spike/sh_bm1 for readers

    // ---- fused layer-2: sparse scan s1t -> s2t (+ sh_bm2) -----------------
    if (sh_spike) {
        if (tid < 32) {
            const int c2 = tid;
            float wr2[16];
#pragma unroll
            for (int i = 0; i < 16; ++i) wr2[i] = one_m * w2[c2 * 16 + i];
            const uint8_t* sb1 = s1t + (size_t)b * 16 * T_STEPS;
            uint4* op2 = (uint4*)(s2t + ((size_t)b * 32 + c2) * T_STEPS);
            const uint4* bmv = (const uint4*)sh_bm1;
            float v = 0.0f;
            for (int sb = 0; sb < 16; ++sb) {
                uint4 bm = bmv[sb];
                if ((bm.x | bm.y | bm.z | bm.w) == 0u) {
                    if (v != 0.0f) {
                        for (int blk = 0; blk < 16 && v != 0.0f; ++blk) {
#pragma unroll
                            for (int j = 0; j < 16; ++j) v *= alpha;
                        }
                    }
                    continue;
                }
                for (int blk = 0; blk < 16; ++blk) {
                    uint32_t d = (blk < 4) ? bm.x : (blk < 8) ? bm.y
                               : (blk < 12) ? bm.z : bm.w;
                    uint32_t byte = (d >> ((blk & 3) * 8)) & 0xffu;
                    if (byte == 0u) {
                        if (v != 0.0f) {
#pragma unroll
                            for (int j = 0; j < 16; ++j) v *= alpha;
                        }
                        continue;
                    }
                    const int tb = sb * 16 + blk;
                    const int t0 = tb * 16;
                    uint4 S[16];
#pragma unroll
                    for (int c = 0; c < 16; ++c)
                        S[c] = *(const uint4*)(sb1 + (size_t)c * T_STEPS + t0);
                    uint32_t w[4] = {0u, 0u, 0u, 0u};
#pragma unroll
                    for (int j = 0; j < 16; ++j) {
                        float xv[16];
#pragma unroll
                        for (int c = 0; c < 16; ++c) {
                            uint32_t dd = (j < 4) ? S[c].x : (j < 8) ? S[c].y
                                        : (j < 12) ? S[c].z : S[c].w;
                            xv[c] = ubf(dd, j & 3);
                        }
                        float p0 = fmaf(wr2[1], xv[1], wr2[0] * xv[0]);
                        p0 = fmaf(wr2[2], xv[2], p0);   p0 = fmaf(wr2[3], xv[3], p0);
                        float p1 = fmaf(wr2[5], xv[5], wr2[4] * xv[4]);
                        p1 = fmaf(wr2[6], xv[6], p1);   p1 = fmaf(wr2[7], xv[7], p1);
                        float p2 = fmaf(wr2[9], xv[9], wr2[8] * xv[8]);
                        p2 = fmaf(wr2[10], xv[10], p2); p2 = fmaf(wr2[11], xv[11], p2);
                        float p3 = fmaf(wr2[13], xv[13], wr2[12] * xv[12]);
                        p3 = fmaf(wr2[14], xv[14], p3); p3 = fmaf(wr2[15], xv[15], p3);
                        float xs = (p0 + p1) + (p2 + p3);
                        float s = lif_step(v, xs, alpha);
                        w[j >> 2] |= ((uint32_t)(int)s) << ((j & 3) * 8);
                    }
                    op2[tb] = make_uint4(w[0], w[1], w[2], w[3]);
                    if (w[0] | w[1] | w[2] | w[3]) { sh_bm2[tb] = 1; sh_flag2 = 1; }
                }
            }
        }
        __syncthreads();   // s2t/sh_bm2/sh_flag2 visible

        // ---- fused layer-3: sparse scan s2t -> out (pre-zeroed) -----------
        if (sh_flag2 && tid < 16) {
            const int c3 = tid;
            const bool active = (c3 < 10);
            float wr3[32];
#pragma unroll
            for (int i = 0; i < 32; ++i)
                wr3[i] = active ? (one_m * w3[c3 * 32 + i]) : 0.0f;
            const uint8_t* sb2 = s2t + (size_t)b * 32 * T_STEPS;
            const uint4* bmv2 = (const uint4*)sh_bm2;
            float* ob = out + (size_t)b * T_STEPS * 10 + c3;
            float v = 0.0f;
            for (int sb = 0; sb < 16; ++sb) {
                uint4 bm = bmv2[sb];
                if ((bm.x | bm.y | bm.z | bm.w) == 0u) {
                    if (v != 0.0f) {
                        for (int blk = 0; blk < 16 && v != 0.0f; ++blk) {
#pragma unroll
                            for (int j = 0; j < 16; ++j) v *= alpha;
                        }
                    }
                    continue;
                }
                for (int blk = 0; blk < 16; ++blk) {
                    uint32_t d = (blk < 4) ? bm.x : (blk < 8) ? bm.y
                               : (blk < 12) ? bm.z : bm.w;
                    uint32_t byte = (d >> ((blk & 3) * 8)) & 0xffu;
                    if (byte == 0u) {
                        if (v != 0.0f) {
#pragma unroll
                            for (int j = 0; j < 16; ++j) v *= alpha;
                        }
                        continue;
                    }
                    const int t0 = (sb * 16 + blk) * 16;
                    uint4 S[32];
#pragma unroll
                    for (int c = 0; c < 32; ++c)
                        S[c] = *(const uint4*)(sb2 + (size_t)c * T_STEPS + t0);
#pragma unroll
                    for (int j = 0; j < 16; ++j) {
                        float xv[32];
#pragma unroll
                        for (int c = 0; c < 32; ++c) {
                            uint32_t dd = (j < 4) ? S[c].x : (j < 8) ? S[c].y
                                        : (j < 12) ? S[c].z : S[c].w;
                            xv[c] = ubf(dd, j & 3);
                        }
                        float p0 = fmaf(wr3[1], xv[1], wr3[0] * xv[0]);
                        p0 = fmaf(wr3[2],  xv[2],  p0); p0 = fmaf(wr3[3],  xv[3],  p0);
                        p0 = fmaf(wr3[4],  xv[4],  p0); p0 = fmaf(wr3[5],  xv[5],  p0);
                        p0 = fmaf(wr3[6],  xv[6],  p0); p0 = fmaf(wr3[7],  xv[7],  p0);
                        float p1 = fmaf(wr3[9], xv[9], wr3[8] * xv[8]);
                        p1 = fmaf(wr3[10], xv[10], p1); p1 = fmaf(wr3[11], xv[11], p1);
                        p1 = fmaf(wr3[12], xv[12], p1); p1 = fmaf(wr3[13], xv[13], p1);
                        p1 = fmaf(wr3[14], xv[14], p1); p1 = fmaf(wr3[15], xv[15], p1);
                        float p2 = fmaf(wr3[17], xv[17], wr3[16] * xv[16]);
                        p2 = fmaf(wr3[18], xv[18], p2); p2 = fmaf(wr3[19], xv[19], p2);
                        p2 = fmaf(wr3[20], xv[20], p2); p2 = fmaf(wr3[21], xv[21], p2);
                        p2 = fmaf(wr3[22], xv[22], p2); p2 = fmaf(wr3[23], xv[23], p2);
                        float p3 = fmaf(wr3[25], xv[25], wr3[24] * xv[24]);
                        p3 = fmaf(wr3[26], xv[26], p3); p3 = fmaf(wr3[27], xv[27], p3);
                        p3 = fmaf(wr3[28], xv[28], p3); p3 = fmaf(wr3[29], xv[29], p3);
                        p3 = fmaf(wr3[30], xv[30], p3); p3 = fmaf(wr3[31], xv[31], p3);
                        float xs = (p0 + p1) + (p2 + p3);
                        float s = lif_step(v, xs, alpha);
                        if (active && s != 0.0f) ob[(size_t)(t0 + j) * 10] = s;
                    }
                }
            }
        }
    }
}

extern "C" void kernel_launch(void* const* d_in, const int* in_sizes, int n_in,
                              void* d_out, int out_size, void* d_ws, size_t ws_size,
                              hipStream_t stream)
{
    const float* data = (const float*)d_in[0];
    const float* w1   = (const float*)d_in[1];
    const float* w2   = (const float*)d_in[2];
    const float* w3   = (const float*)d_in[3];
    float* out = (float*)d_out;

    // ws layout (48 MiB):
    //   [0, 16M)    s1t  u8 [256][16][4096]  (dense-zeroed only for bad b)
    //   [16M, 48M)  s2t  u8 [256][32][4096]  (sparse: only bm2-set blocks valid)
    uint8_t* ws  = (uint8_t*)d_ws;
    uint8_t* s1t = ws;
    uint8_t* s2t = ws + (16u << 20);

    const float alpha  = expf(-1.0f / 20.0f);
    const float one_m  = 1.0f - alpha;
    const float alpha4 = expf(-4.0f / 20.0f);

    fused<<<BATCH, 1024, 0, stream>>>(data, w1, w2, w3, out, s1t, s2t,
                                      alpha, one_m, alpha4);
}